// Round 17
// baseline (412.688 us; speedup 1.0000x reference)
//
#include <hip/hip_runtime.h>
#include <hip/hip_bf16.h>
#include <math.h>

#define NN 16384
#define NE 262144
#define NB 64
#define FD 32
#define NT 8
#define NL 3
#define NH 128
#define EPSV 1e-5f

typedef unsigned short u16;
typedef unsigned int u32;
typedef long long i64;

static __device__ __forceinline__ float us2f(u16 u){
  union { u32 i; float f; } z; z.i = ((u32)u) << 16; return z.f;
}
static __device__ __forceinline__ u16 f2us(float v){
  __hip_bfloat16 b = __float2bfloat16(v);
  return *(u16*)&b;
}

__global__ void k_diag(float* out, float v){
  int i = threadIdx.x;
  if (i < 128) out[i] = v;
}

// ---------- weight dtype detect + int width detect (merged) ----------
__global__ __launch_bounds__(256) void k_det(const u16* __restrict__ ne, const int* __restrict__ ei_raw,
                                             int* __restrict__ flags){
  __shared__ int red[256];
  const int tid = threadIdx.x;
  if (blockIdx.x == 0){
    __shared__ float redf[256];
    float m = 0.f;
    for (int i=tid; i<1024; i+=256) m = fmaxf(m, fabsf(us2f(ne[i])));
    redf[tid]=m; __syncthreads();
    for (int off=128; off>0; off>>=1){ if (tid<off) redf[tid]=fmaxf(redf[tid],redf[tid+off]); __syncthreads(); }
    if (tid==0) flags[0] = (redf[0] > 100.f) ? 1 : 0;
    __syncthreads();
  }
  int i = blockIdx.x*256 + tid;
  int c = (i < NE && ei_raw[2*i+1] == 0) ? 1 : 0;
  red[tid]=c; __syncthreads();
  for (int off=128; off>0; off>>=1){ if (tid<off) red[tid]+=red[tid+off]; __syncthreads(); }
  if (tid==0) atomicAdd(&flags[4], red[0]);
}

// ---------- canonicalize ints + degree count fused ----------
struct IJobs { const void* src[4]; int* dst[4]; int cnt[4]; };
__global__ __launch_bounds__(256) void k_cvt_int(IJobs jb, const int* __restrict__ flags,
                                                 int* __restrict__ deg, int total){
  int i = blockIdx.x*256 + threadIdx.x;
  if (i >= total) return;
  const int m = (flags[4] > NE/4) ? 1 : 0;
  int a = 0, off = i;
  while (off >= jb.cnt[a]){ off -= jb.cnt[a]; a++; }
  int v = m ? (int)((const i64*)jb.src[a])[off] : ((const int*)jb.src[a])[off];
  jb.dst[a][off] = v;
  if (a == 1 && off >= NE && v >= 0 && v < NN) atomicAdd(&deg[v], 1);
}

struct Jobs { const void* src[20]; float* dst[20]; int cnt[20]; };
__global__ __launch_bounds__(256) void k_cvt(Jobs jb, const int* __restrict__ flags, int total){
  int i = blockIdx.x*256 + threadIdx.x;
  if (i >= total) return;
  const int m = flags[0];
  int a = 0, off = i;
  while (off >= jb.cnt[a]){ off -= jb.cnt[a]; a++; }
  float v = m ? ((const float*)jb.src[a])[off]
              : us2f(((const u16*)jb.src[a])[off]);
  jb.dst[a][off] = v;
}

// ---------------- CSR scan + avg-log fused ----------------
__global__ __launch_bounds__(256) void k_scan(const int* __restrict__ deg, int* __restrict__ offs,
                                              double* __restrict__ lsum){
  __shared__ int part[257];
  __shared__ double red[256];
  const int tid = threadIdx.x;
  int s = 0; double ls = 0.0;
  for (int i=0;i<64;i++){ int d = deg[tid*64+i]; s += d; ls += log((double)d + 1.0); }
  part[tid+1] = s; red[tid] = ls;
  __syncthreads();
  if (tid==0){ part[0]=0; for (int i=1;i<=256;i++) part[i]+=part[i-1]; }
  for (int off=128; off>0; off>>=1){ if (tid<off) red[tid]+=red[tid+off]; __syncthreads(); }
  if (tid==0) *lsum = red[0] / (double)NN;
  __syncthreads();
  int run = part[tid];
  for (int i=0;i<64;i++){ offs[tid*64+i]=run; run+=deg[tid*64+i]; }
  if (tid==255) offs[NN]=run;
}

__global__ void k_fill(const int* __restrict__ src, const int* __restrict__ dst,
                       const int* __restrict__ ea_in, const int* __restrict__ offs,
                       int* __restrict__ cursor, int* __restrict__ esrc, int* __restrict__ eatt){
  int e = blockIdx.x*256 + threadIdx.x;
  if (e < NE){
    int d = dst[e];
    int pslot = atomicAdd(&cursor[d], 1);
    int idx = offs[d] + pslot;
    esrc[idx] = src[e];
    eatt[idx] = ea_in[e];
  }
}

// ---------------- scalers + pool bounds fused ----------------
__global__ void k_nodeprep(const int* __restrict__ deg, const double* __restrict__ lsum,
                           const int* __restrict__ batch,
                           float* __restrict__ amp, float* __restrict__ attn, float* __restrict__ invc,
                           int* __restrict__ bstart){
  int n = blockIdx.x*256 + threadIdx.x;
  if (n >= NN) return;
  float avg = (float)(*lsum);
  int d = deg[n]; int dc = d > 0 ? d : 1;
  float la = logf((float)dc + 1.0f);
  amp[n] = la/avg; attn[n] = avg/la; invc[n] = 1.0f/(float)dc;
  int b = batch[n];
  int prev = (n==0) ? -1 : batch[n-1];
  for (int v=prev+1; v<=b; v++) bstart[v]=n;
  if (n==NN-1) for (int v=b+1; v<=NB; v++) bstart[v]=NN;
}

// ---------------- fused eenc + etab ----------------
__global__ __launch_bounds__(256) void k_etab3(const float* __restrict__ ee, const float* __restrict__ Wee,
                      const float* __restrict__ bee, const float* __restrict__ Wpre,
                      float* __restrict__ etab, int l){
  __shared__ float el[16*FD];
  const int tid = threadIdx.x;
  for (int i=tid; i<16*FD; i+=256){
    int a = i>>5, f2 = i&31;
    float acc = bee[l*FD + f2];
    for (int c2=0; c2<16; c2++)
      acc = fmaf(ee[a*16+c2], Wee[(l*16+c2)*FD+f2], acc);
    el[i] = acc;
  }
  __syncthreads();
  int i = blockIdx.x*256 + tid;
  int a = i>>8, dd = i&255, t = dd>>5, f = dd&31;
  float acc = 0.f;
  for (int f2=0; f2<FD; f2++)
    acc = fmaf(el[a*FD+f2], Wpre[((l*NT+t)*96 + 64 + f2)*FD + f], acc);
  etab[i] = acc;
}

// ---------------- per-node pre: BN(prev z)/embed -> h ; nbase bf16 ; psrc bf16 ----------------
__global__ __launch_bounds__(256) void k_pre(
    const float* __restrict__ z, const double* __restrict__ st,
    const float* __restrict__ bng, const float* __restrict__ bnb,
    const int* __restrict__ x, const float* __restrict__ emb,
    const float* __restrict__ Wpre, const float* __restrict__ bpre,
    float* __restrict__ h, u16* __restrict__ nbaseH, u16* __restrict__ psrcH, int l)
{
  __shared__ float hl[64*FD];
  __shared__ float scl[FD], shl[FD];
  const int tid = threadIdx.x;
  const int n0 = blockIdx.x*64;
  if (l == 0){
    for (int i=tid; i<64*FD; i+=256)
      hl[i] = emb[x[n0+(i>>5)]*FD + (i&31)];
  } else {
    if (tid < FD){
      const double* stL = st + (l-1)*64;
      double mu = stL[tid] * (1.0/(double)NN);
      double var = stL[32+tid] * (1.0/(double)NN) - mu*mu;
      float sc = bng[(l-1)*FD+tid]*rsqrtf(fmaxf((float)var,0.f)+EPSV);
      scl[tid]=sc; shl[tid]=bnb[(l-1)*FD+tid]-(float)mu*sc;
    }
    __syncthreads();
    for (int i=tid; i<64*FD; i+=256){
      int f = i&31;
      hl[i] = fmaxf(z[n0*FD+i]*scl[f]+shl[f], 0.f);
    }
  }
  __syncthreads();
  for (int i=tid; i<64*FD; i+=256) h[n0*FD+i] = hl[i];
  const int t = tid>>5, f = tid&31;
  float wd[32], ws[32];
  #pragma unroll
  for (int c=0;c<FD;c++){
    wd[c] = Wpre[((l*NT+t)*96 + c)*FD + f];
    ws[c] = Wpre[((l*NT+t)*96 + 32 + c)*FD + f];
  }
  const float bb = bpre[(l*NT+t)*FD + f];
  for (int nn=0; nn<64; nn++){
    float ad=bb, as=0.f;
    #pragma unroll
    for (int c=0;c<FD;c++){ float hv=hl[nn*FD+c]; ad=fmaf(hv,wd[c],ad); as=fmaf(hv,ws[c],as); }
    const int n = n0+nn;
    nbaseH[(size_t)n*256+tid]=f2us(ad);
    psrcH[(size_t)n*256+tid]=f2us(as);
  }
}

// ---------------- fused aggregation + post-MLP + Wlin + BN-stats ----------------
__global__ __launch_bounds__(1024) void k_agg(
    const u16* __restrict__ nbaseH, const u16* __restrict__ psrcH,
    const float* __restrict__ etab,
    const int* __restrict__ esrc, const int* __restrict__ eatt, const int* __restrict__ offs,
    const float* __restrict__ h, const float* __restrict__ amp,
    const float* __restrict__ attn, const float* __restrict__ invc,
    const float* __restrict__ Wpost, const float* __restrict__ bpost,
    const float* __restrict__ Wlin, const float* __restrict__ blin,
    float* __restrict__ z, double* __restrict__ st, int l)
{
  __shared__ u16 wp[13312];
  __shared__ float wl[1024];
  __shared__ float bpo[32], bli[32];
  __shared__ float s1[16*32], s2[16*32];
  const int tid = threadIdx.x;
  const float* WpL = Wpost + (size_t)l*13312;
  for (int i=tid;i<13312;i+=1024) wp[i] = (u16)(__float_as_uint(WpL[i])>>16);
  if (tid < 1024) wl[tid] = Wlin[l*1024+tid];
  if (tid<32){ bpo[tid]=bpost[l*32+tid]; bli[tid]=blin[l*32+tid]; }
  __syncthreads();
  const int wid = tid>>6, lane = tid&63;
  const int t = lane>>3, q = lane&7;
  const int n = blockIdx.x*16 + wid;
  const int o0 = offs[n], o1 = offs[n+1];
  float bs[4];
  {
    ushort4 b4 = *(const ushort4*)(nbaseH + (size_t)n*256 + lane*4);
    const u16* bb=(const u16*)&b4;
    #pragma unroll
    for (int k=0;k<4;k++) bs[k] = us2f(bb[k]);
  }
  float sum[4]={0,0,0,0}, sq[4]={0,0,0,0}, mn[4], mx[4];
  #pragma unroll
  for (int k=0;k<4;k++){ mn[k]=__builtin_inff(); mx[k]=-__builtin_inff(); }
  int j = o0;
  for (; j+3 < o1; j+=4){
    const int s0=esrc[j],   s1_=esrc[j+1], s2_=esrc[j+2], s3=esrc[j+3];
    const int a0=eatt[j],   a1=eatt[j+1], a2=eatt[j+2], a3=eatt[j+3];
    ushort4 p0 = *(const ushort4*)(psrcH + (size_t)s0*256 + lane*4);
    ushort4 p1 = *(const ushort4*)(psrcH + (size_t)s1_*256 + lane*4);
    ushort4 p2 = *(const ushort4*)(psrcH + (size_t)s2_*256 + lane*4);
    ushort4 p3 = *(const ushort4*)(psrcH + (size_t)s3*256 + lane*4);
    float4 e0 = *(const float4*)(etab + a0*256 + lane*4);
    float4 e1 = *(const float4*)(etab + a1*256 + lane*4);
    float4 e2 = *(const float4*)(etab + a2*256 + lane*4);
    float4 e3 = *(const float4*)(etab + a3*256 + lane*4);
    const u16* pp0=(const u16*)&p0; const float* ee0=(const float*)&e0;
    const u16* pp1=(const u16*)&p1; const float* ee1=(const float*)&e1;
    const u16* pp2=(const u16*)&p2; const float* ee2=(const float*)&e2;
    const u16* pp3=(const u16*)&p3; const float* ee3=(const float*)&e3;
    #pragma unroll
    for (int k=0;k<4;k++){
      float v0 = bs[k] + us2f(pp0[k]) + ee0[k];
      float v1 = bs[k] + us2f(pp1[k]) + ee1[k];
      float v2 = bs[k] + us2f(pp2[k]) + ee2[k];
      float v3 = bs[k] + us2f(pp3[k]) + ee3[k];
      sum[k] += (v0+v1)+(v2+v3);
      sq[k] = fmaf(v0,v0,sq[k]); sq[k] = fmaf(v1,v1,sq[k]);
      sq[k] = fmaf(v2,v2,sq[k]); sq[k] = fmaf(v3,v3,sq[k]);
      mn[k] = fminf(mn[k], fminf(fminf(v0,v1), fminf(v2,v3)));
      mx[k] = fmaxf(mx[k], fmaxf(fmaxf(v0,v1), fmaxf(v2,v3)));
    }
  }
  for (; j < o1; j++){
    const int s = esrc[j];
    const int a = eatt[j];
    ushort4 pv4 = *(const ushort4*)(psrcH + (size_t)s*256 + lane*4);
    float4 ev4 = *(const float4*)(etab + a*256 + lane*4);
    const u16* pv=(const u16*)&pv4; const float* ev=(const float*)&ev4;
    #pragma unroll
    for (int k=0;k<4;k++){
      float v = bs[k] + us2f(pv[k]) + ev[k];
      sum[k]+=v; sq[k]=fmaf(v,v,sq[k]); mn[k]=fminf(mn[k],v); mx[k]=fmaxf(mx[k],v);
    }
  }
  const int dg = o1-o0;
  const float ic = invc[n];
  float aggv[4][4];
  #pragma unroll
  for (int k=0;k<4;k++){
    float mean = sum[k]*ic;
    float ms = sq[k]*ic;
    float var = fmaxf(ms - mean*mean, 0.f);
    aggv[0][k]=mean;
    aggv[1][k]=(dg>0)?mn[k]:0.f;
    aggv[2][k]=(dg>0)?mx[k]:0.f;
    aggv[3][k]=sqrtf(var+EPSV);
  }
  const float av = amp[n], at_ = attn[n];
  float acc[4]={0,0,0,0};
  float hv[4]; *(float4*)hv = *(const float4*)(h + n*FD + q*4);
  #pragma unroll
  for (int k=0;k<4;k++){
    int c = q*4+k;
    ushort4 w4 = *(const ushort4*)&wp[(t*416+c)*4];
    const u16* ww = (const u16*)&w4;
    #pragma unroll
    for (int jj=0;jj<4;jj++)
      acc[jj] = fmaf(hv[k], us2f(ww[jj]), acc[jj]);
  }
  #pragma unroll
  for (int g=0; g<4; g++){
    #pragma unroll
    for (int k=0;k<4;k++){
      float a_ = aggv[g][k];
      int rb = 32 + g*32 + q*4 + k;
      ushort4 w0 = *(const ushort4*)&wp[(t*416+rb)*4];
      ushort4 w1 = *(const ushort4*)&wp[(t*416+rb+128)*4];
      ushort4 w2 = *(const ushort4*)&wp[(t*416+rb+256)*4];
      const u16* q0=(const u16*)&w0;
      const u16* q1=(const u16*)&w1;
      const u16* q2=(const u16*)&w2;
      #pragma unroll
      for (int jj=0;jj<4;jj++){
        float w = us2f(q0[jj]) + av*us2f(q1[jj]) + at_*us2f(q2[jj]);
        acc[jj] = fmaf(a_, w, acc[jj]);
      }
    }
  }
  #pragma unroll
  for (int jj=0;jj<4;jj++){
    acc[jj] += __shfl_xor(acc[jj], 1);
    acc[jj] += __shfl_xor(acc[jj], 2);
    acc[jj] += __shfl_xor(acc[jj], 4);
    acc[jj] += bpo[t*4+jj];
  }
  float zv = 0.f;
  #pragma unroll
  for (int dp=0; dp<32; dp++){
    float v = __shfl(acc[dp&3], (dp>>2)*8);
    zv = fmaf(v, wl[dp*32 + (lane&31)], zv);
  }
  float zfin = zv + bli[lane&31];
  if (lane < 32){
    z[n*FD + lane] = zfin;
    s1[wid*32+lane] = zfin;
    s2[wid*32+lane] = zfin*zfin;
  }
  __syncthreads();
  if (tid < 32){
    float a1=0.f, a2=0.f;
    #pragma unroll
    for (int w=0; w<16; w++){ a1 += s1[w*32+tid]; a2 += s2[w*32+tid]; }
    atomicAdd(&st[l*64+tid],    (double)a1);
    atomicAdd(&st[l*64+32+tid], (double)a2);
  }
}

// ---------------- pooling with fused final BN ----------------
__global__ __launch_bounds__(256) void k_pool2(const float* __restrict__ z, const double* __restrict__ st,
                                               const float* __restrict__ bng, const float* __restrict__ bnb,
                                               const int* __restrict__ bstart, float* __restrict__ g){
  __shared__ float acc[8][FD];
  __shared__ float scl[FD], shl[FD];
  const int b = blockIdx.x;
  const int tid = threadIdx.x;
  const int f = tid&31, rg = tid>>5;
  if (tid < FD){
    const double* stL = st + (NL-1)*64;
    double mu = stL[tid] * (1.0/(double)NN);
    double var = stL[32+tid] * (1.0/(double)NN) - mu*mu;
    float sc = bng[(NL-1)*FD+tid]*rsqrtf(fmaxf((float)var,0.f)+EPSV);
    scl[tid]=sc; shl[tid]=bnb[(NL-1)*FD+tid]-(float)mu*sc;
  }
  __syncthreads();
  const int lo = bstart[b], hi = bstart[b+1];
  float s = 0.f;
  for (int n=lo+rg; n<hi; n+=8) s += fmaxf(z[n*FD+f]*scl[f]+shl[f], 0.f);
  acc[rg][f] = s; __syncthreads();
  if (rg == 0){
    float t = 0.f;
    for (int r=0;r<8;r++) t += acc[r][f];
    g[b*FD+f] = t;
  }
}

// ---------------- head: grid-parallel kernels ----------------
__global__ __launch_bounds__(256) void k_hgemm(const float* __restrict__ in, const float* __restrict__ W,
                                               const float* __restrict__ bias, float* __restrict__ outp,
                                               int IN){
  int o = blockIdx.x*256 + threadIdx.x;
  int b = o>>7, hh = o&127;
  float acc = bias[hh];
  for (int c=0;c<IN;c++) acc = fmaf(in[b*IN+c], W[c*NH+hh], acc);
  outp[o] = acc;
}

__global__ __launch_bounds__(512) void k_hbn(float* __restrict__ buf,
                                             const float* __restrict__ gvec, const float* __restrict__ bvec){
  __shared__ float scf[NH], shf[NH];
  const int tid = threadIdx.x;
  const int f = tid>>2, part = tid&3;
  double s1=0.0, s2=0.0;
  for (int b=part*16; b<part*16+16; b++){
    double v = (double)buf[b*NH+f]; s1+=v; s2+=v*v;
  }
  s1 += __shfl_xor(s1, 1); s2 += __shfl_xor(s2, 1);
  s1 += __shfl_xor(s1, 2); s2 += __shfl_xor(s2, 2);
  if (part==0){
    double mu = s1/(double)NB;
    double var = s2/(double)NB - mu*mu;
    float varf = fmaxf((float)var, 0.f);
    float sc = gvec[f]*rsqrtf(varf+EPSV);
    scf[f]=sc; shf[f]=bvec[f]-(float)mu*sc;
  }
  __syncthreads();
  for (int i=tid; i<NB*NH; i+=512){
    int hh = i&127;
    buf[i] = fmaxf(buf[i]*scf[hh]+shf[hh], 0.f);
  }
}

__global__ __launch_bounds__(64) void k_hfin(const float* __restrict__ buf, const float* __restrict__ Wf,
                                             const float* __restrict__ bfv, float* __restrict__ out){
  int b = threadIdx.x;
  float acc = bfv[0];
  for (int c=0;c<NH;c++) acc = fmaf(buf[b*NH+c], Wf[c], acc);
  out[NB+b] = acc;
  out[b]    = 1.f/(1.f+expf(-acc));
}

extern "C" void kernel_launch(void* const* d_in, const int* in_sizes, int n_in,
                              void* d_out, int out_size, void* d_ws, size_t ws_size,
                              hipStream_t stream)
{
  float* out = (float*)d_out;

  static const int EXP_SZ[24] = {16384, 524288, 262144, 16384, 1024, 256, 1536, 96,
                                 73728, 768, 39936, 96, 3072, 96, 96, 96,
                                 4096, 128, 32768, 256, 384, 384, 128, 1};
  int bad = -1;
  if (n_in != 24) bad = 24;
  else for (int i=0;i<24;i++){ if (in_sizes[i] != EXP_SZ[i]){ bad = i; break; } }
  if (bad >= 0){
    k_diag<<<1, 128, 0, stream>>>(out, 512.0f + 8.0f*(float)bad);
    return;
  }

  char* p = (char*)d_ws;
  auto carve = [&](size_t bytes)->char*{ char* r = p; p += (bytes + 255) & ~(size_t)255; return r; };
  // zero-region: flags, st, deg, cursor -> one memset
  int*    flags = (int*)carve(256);
  double* st1   = (double*)carve(3*64*8);
  int*    deg   = (int*)carve((size_t)NN*4);
  int*    cursor= (int*)carve((size_t)NN*4);
  size_t  zspan = (size_t)(((char*)cursor + ((NN*4+255)&~(size_t)255)) - (char*)flags);
  int*    offs  = (int*)carve((size_t)(NN+1)*4);
  int*    esrc  = (int*)carve((size_t)NE*4);
  int*    eatt  = (int*)carve((size_t)NE*4);
  int*    bstart= (int*)carve((size_t)(NB+1)*4);
  float*  h     = (float*)carve((size_t)NN*FD*4);
  float*  z     = (float*)carve((size_t)NN*FD*4);
  u16*    nbaseH= (u16*)carve((size_t)NN*256*2);
  u16*    psrcH = (u16*)carve((size_t)NN*256*2);
  float*  etab  = (float*)carve(4096*4);
  float*  amp   = (float*)carve((size_t)NN*4);
  float*  attn  = (float*)carve((size_t)NN*4);
  float*  invc  = (float*)carve((size_t)NN*4);
  double* lsum  = (double*)carve(8);
  float*  gp    = (float*)carve((size_t)NB*FD*4);
  float*  t0    = (float*)carve((size_t)NB*NH*4);
  float*  t1    = (float*)carve((size_t)NB*NH*4);
  float*  t2    = (float*)carve((size_t)NB*NH*4);
  int*    cx    = (int*)carve((size_t)NN*4);
  int*    cei   = (int*)carve((size_t)2*NE*4);
  int*    cea   = (int*)carve((size_t)NE*4);
  int*    cbatch= (int*)carve((size_t)NN*4);

  Jobs jb;
  float* wptr[24];
  int total = 0;
  {
    float* cur = (float*)carve(700*1024);
    for (int i=4; i<24; i++){
      jb.src[i-4] = d_in[i];
      jb.dst[i-4] = cur;
      jb.cnt[i-4] = in_sizes[i];
      wptr[i] = cur;
      cur += in_sizes[i];
      total += in_sizes[i];
    }
  }
  const size_t need = (size_t)(p - (char*)d_ws);
  if (ws_size < need){
    k_diag<<<1, 128, 0, stream>>>(out, -2000.0f - (float)(ws_size >> 20));
    return;
  }

  IJobs ij;
  ij.src[0]=d_in[0]; ij.dst[0]=cx;     ij.cnt[0]=NN;
  ij.src[1]=d_in[1]; ij.dst[1]=cei;    ij.cnt[1]=2*NE;
  ij.src[2]=d_in[2]; ij.dst[2]=cea;    ij.cnt[2]=NE;
  ij.src[3]=d_in[3]; ij.dst[3]=cbatch; ij.cnt[3]=NN;
  const int itotal = NN + 2*NE + NE + NN;

  const float* ne_f   = wptr[4];
  const float* ee_f   = wptr[5];
  const float* Wee_f  = wptr[6];
  const float* bee_f  = wptr[7];
  const float* Wpre_f = wptr[8];
  const float* bpre_f = wptr[9];
  const float* Wpost_f= wptr[10];
  const float* bpost_f= wptr[11];
  const float* Wlin_f = wptr[12];
  const float* blin_f = wptr[13];
  const float* bng_f  = wptr[14];
  const float* bnb_f  = wptr[15];
  const float* Wm0_f  = wptr[16];
  const float* bm0_f  = wptr[17];
  const float* Wmh_f  = wptr[18];
  const float* bmh_f  = wptr[19];
  const float* bnmg_f = wptr[20];
  const float* bnmb_f = wptr[21];
  const float* Wf_f   = wptr[22];
  const float* bf_f   = wptr[23];

  hipMemsetAsync(flags, 0, zspan, stream);

  k_det<<<NE/256, 256, 0, stream>>>((const u16*)d_in[4], (const int*)d_in[1], flags);
  k_cvt_int<<<(itotal+255)/256, 256, 0, stream>>>(ij, flags, deg, itotal);
  k_cvt<<<(total+255)/256, 256, 0, stream>>>(jb, flags, total);

  k_scan<<<1, 256, 0, stream>>>(deg, offs, lsum);
  k_fill<<<NE/256, 256, 0, stream>>>(cei, cei+NE, cea, offs, cursor, esrc, eatt);
  k_nodeprep<<<NN/256, 256, 0, stream>>>(deg, lsum, cbatch, amp, attn, invc, bstart);

  for (int l=0; l<NL; l++){
    k_etab3<<<16, 256, 0, stream>>>(ee_f, Wee_f, bee_f, Wpre_f, etab, l);
    k_pre<<<NN/64, 256, 0, stream>>>(z, st1, bng_f, bnb_f, cx, ne_f, Wpre_f, bpre_f,
                                     h, nbaseH, psrcH, l);
    k_agg<<<NN/16, 1024, 0, stream>>>(nbaseH, psrcH, etab, esrc, eatt, offs, h, amp, attn, invc,
                                      Wpost_f, bpost_f, Wlin_f, blin_f, z, st1, l);
  }

  k_pool2<<<NB, 256, 0, stream>>>(z, st1, bng_f, bnb_f, bstart, gp);
  k_hgemm<<<32, 256, 0, stream>>>(gp, Wm0_f, bm0_f, t0, FD);
  k_hbn<<<1, 512, 0, stream>>>(t0, bnmg_f, bnmb_f);
  k_hgemm<<<32, 256, 0, stream>>>(t0, Wmh_f, bmh_f, t1, NH);
  k_hbn<<<1, 512, 0, stream>>>(t1, bnmg_f+NH, bnmb_f+NH);
  k_hgemm<<<32, 256, 0, stream>>>(t1, Wmh_f+NH*NH, bmh_f+NH, t2, NH);
  k_hbn<<<1, 512, 0, stream>>>(t2, bnmg_f+2*NH, bnmb_f+2*NH);
  k_hfin<<<1, 64, 0, stream>>>(t2, Wf_f, bf_f, out);
}

// Round 18
// 336.222 us; speedup vs baseline: 1.2274x; 1.2274x over previous
//
#include <hip/hip_runtime.h>
#include <hip/hip_bf16.h>
#include <math.h>

#define NN 16384
#define NE 262144
#define NB 64
#define FD 32
#define NT 8
#define NL 3
#define NH 128
#define EPSV 1e-5f

typedef unsigned short u16;
typedef unsigned int u32;
typedef long long i64;

static __device__ __forceinline__ float us2f(u16 u){
  union { u32 i; float f; } z; z.i = ((u32)u) << 16; return z.f;
}
static __device__ __forceinline__ u16 f2us(float v){
  __hip_bfloat16 b = __float2bfloat16(v);
  return *(u16*)&b;
}

__global__ void k_diag(float* out, float v){
  int i = threadIdx.x;
  if (i < 128) out[i] = v;
}

// ---------- weight dtype detect + int width detect (merged) ----------
__global__ __launch_bounds__(256) void k_det(const u16* __restrict__ ne, const int* __restrict__ ei_raw,
                                             int* __restrict__ flags){
  __shared__ int red[256];
  const int tid = threadIdx.x;
  if (blockIdx.x == 0){
    __shared__ float redf[256];
    float m = 0.f;
    for (int i=tid; i<1024; i+=256) m = fmaxf(m, fabsf(us2f(ne[i])));
    redf[tid]=m; __syncthreads();
    for (int off=128; off>0; off>>=1){ if (tid<off) redf[tid]=fmaxf(redf[tid],redf[tid+off]); __syncthreads(); }
    if (tid==0) flags[0] = (redf[0] > 100.f) ? 1 : 0;
    __syncthreads();
  }
  int i = blockIdx.x*256 + tid;
  int c = (i < NE && ei_raw[2*i+1] == 0) ? 1 : 0;
  red[tid]=c; __syncthreads();
  for (int off=128; off>0; off>>=1){ if (tid<off) red[tid]+=red[tid+off]; __syncthreads(); }
  if (tid==0) atomicAdd(&flags[4], red[0]);
}

// ---------- canonicalize ints + degree count fused ----------
struct IJobs { const void* src[4]; int* dst[4]; int cnt[4]; };
__global__ __launch_bounds__(256) void k_cvt_int(IJobs jb, const int* __restrict__ flags,
                                                 int* __restrict__ deg, int total){
  int i = blockIdx.x*256 + threadIdx.x;
  if (i >= total) return;
  const int m = (flags[4] > NE/4) ? 1 : 0;
  int a = 0, off = i;
  while (off >= jb.cnt[a]){ off -= jb.cnt[a]; a++; }
  int v = m ? (int)((const i64*)jb.src[a])[off] : ((const int*)jb.src[a])[off];
  jb.dst[a][off] = v;
  if (a == 1 && off >= NE && v >= 0 && v < NN) atomicAdd(&deg[v], 1);
}

struct Jobs { const void* src[20]; float* dst[20]; int cnt[20]; };
__global__ __launch_bounds__(256) void k_cvt(Jobs jb, const int* __restrict__ flags, int total){
  int i = blockIdx.x*256 + threadIdx.x;
  if (i >= total) return;
  const int m = flags[0];
  int a = 0, off = i;
  while (off >= jb.cnt[a]){ off -= jb.cnt[a]; a++; }
  float v = m ? ((const float*)jb.src[a])[off]
              : us2f(((const u16*)jb.src[a])[off]);
  jb.dst[a][off] = v;
}

// ---------------- CSR scan + avg-log fused ----------------
__global__ __launch_bounds__(256) void k_scan(const int* __restrict__ deg, int* __restrict__ offs,
                                              double* __restrict__ lsum){
  __shared__ int part[257];
  __shared__ double red[256];
  const int tid = threadIdx.x;
  int s = 0; double ls = 0.0;
  for (int i=0;i<64;i++){ int d = deg[tid*64+i]; s += d; ls += log((double)d + 1.0); }
  part[tid+1] = s; red[tid] = ls;
  __syncthreads();
  if (tid==0){ part[0]=0; for (int i=1;i<=256;i++) part[i]+=part[i-1]; }
  for (int off=128; off>0; off>>=1){ if (tid<off) red[tid]+=red[tid+off]; __syncthreads(); }
  if (tid==0) *lsum = red[0] / (double)NN;
  __syncthreads();
  int run = part[tid];
  for (int i=0;i<64;i++){ offs[tid*64+i]=run; run+=deg[tid*64+i]; }
  if (tid==255) offs[NN]=run;
}

__global__ void k_fill(const int* __restrict__ src, const int* __restrict__ dst,
                       const int* __restrict__ ea_in, const int* __restrict__ offs,
                       int* __restrict__ cursor, int* __restrict__ esrc, int* __restrict__ eatt){
  int e = blockIdx.x*256 + threadIdx.x;
  if (e < NE){
    int d = dst[e];
    int pslot = atomicAdd(&cursor[d], 1);
    int idx = offs[d] + pslot;
    esrc[idx] = src[e];
    eatt[idx] = ea_in[e];
  }
}

// ---------------- scalers + pool bounds fused ----------------
__global__ void k_nodeprep(const int* __restrict__ deg, const double* __restrict__ lsum,
                           const int* __restrict__ batch,
                           float* __restrict__ amp, float* __restrict__ attn, float* __restrict__ invc,
                           int* __restrict__ bstart){
  int n = blockIdx.x*256 + threadIdx.x;
  if (n >= NN) return;
  float avg = (float)(*lsum);
  int d = deg[n]; int dc = d > 0 ? d : 1;
  float la = logf((float)dc + 1.0f);
  amp[n] = la/avg; attn[n] = avg/la; invc[n] = 1.0f/(float)dc;
  int b = batch[n];
  int prev = (n==0) ? -1 : batch[n-1];
  for (int v=prev+1; v<=b; v++) bstart[v]=n;
  if (n==NN-1) for (int v=b+1; v<=NB; v++) bstart[v]=NN;
}

// ---------------- per-node pre (+16 tail blocks compute etab) ----------------
__global__ __launch_bounds__(256) void k_pre(
    const float* __restrict__ z, const double* __restrict__ st,
    const float* __restrict__ bng, const float* __restrict__ bnb,
    const int* __restrict__ x, const float* __restrict__ emb,
    const float* __restrict__ ee, const float* __restrict__ Wee, const float* __restrict__ bee,
    const float* __restrict__ Wpre, const float* __restrict__ bpre,
    float* __restrict__ h, float* __restrict__ nbase, u16* __restrict__ psrcH,
    float* __restrict__ etab, int l)
{
  const int tid = threadIdx.x;
  if (blockIdx.x >= NN/64){
    // etab blocks: 16 blocks x 256 threads = 4096 entries
    __shared__ float el[16*FD];
    for (int i=tid; i<16*FD; i+=256){
      int a = i>>5, f2 = i&31;
      float acc = bee[l*FD + f2];
      for (int c2=0; c2<16; c2++)
        acc = fmaf(ee[a*16+c2], Wee[(l*16+c2)*FD+f2], acc);
      el[i] = acc;
    }
    __syncthreads();
    int i = (blockIdx.x - NN/64)*256 + tid;
    int a = i>>8, dd = i&255, t = dd>>5, f = dd&31;
    float acc = 0.f;
    for (int f2=0; f2<FD; f2++)
      acc = fmaf(el[a*FD+f2], Wpre[((l*NT+t)*96 + 64 + f2)*FD + f], acc);
    etab[i] = acc;
    return;
  }
  __shared__ float hl[64*FD];
  __shared__ float scl[FD], shl[FD];
  const int n0 = blockIdx.x*64;
  if (l == 0){
    for (int i=tid; i<64*FD; i+=256)
      hl[i] = emb[x[n0+(i>>5)]*FD + (i&31)];
  } else {
    if (tid < FD){
      const double* stL = st + (l-1)*64;
      double mu = stL[tid] * (1.0/(double)NN);
      double var = stL[32+tid] * (1.0/(double)NN) - mu*mu;
      float sc = bng[(l-1)*FD+tid]*rsqrtf(fmaxf((float)var,0.f)+EPSV);
      scl[tid]=sc; shl[tid]=bnb[(l-1)*FD+tid]-(float)mu*sc;
    }
    __syncthreads();
    for (int i=tid; i<64*FD; i+=256){
      int f = i&31;
      hl[i] = fmaxf(z[n0*FD+i]*scl[f]+shl[f], 0.f);
    }
  }
  __syncthreads();
  for (int i=tid; i<64*FD; i+=256) h[n0*FD+i] = hl[i];
  const int t = tid>>5, f = tid&31;
  float wd[32], ws[32];
  #pragma unroll
  for (int c=0;c<FD;c++){
    wd[c] = Wpre[((l*NT+t)*96 + c)*FD + f];
    ws[c] = Wpre[((l*NT+t)*96 + 32 + c)*FD + f];
  }
  const float bb = bpre[(l*NT+t)*FD + f];
  for (int nn=0; nn<64; nn++){
    float ad=bb, as=0.f;
    #pragma unroll
    for (int c=0;c<FD;c++){ float hv=hl[nn*FD+c]; ad=fmaf(hv,wd[c],ad); as=fmaf(hv,ws[c],as); }
    const int n = n0+nn;
    nbase[(size_t)n*256+tid]=ad;
    psrcH[(size_t)n*256+tid]=f2us(as);
  }
}

// ---------------- fused aggregation + post-MLP + Wlin + BN-stats ----------------
__global__ __launch_bounds__(1024) void k_agg(
    const float* __restrict__ nbase, const u16* __restrict__ psrcH,
    const float* __restrict__ etab,
    const int* __restrict__ esrc, const int* __restrict__ eatt, const int* __restrict__ offs,
    const float* __restrict__ h, const float* __restrict__ amp,
    const float* __restrict__ attn, const float* __restrict__ invc,
    const float* __restrict__ Wpost, const float* __restrict__ bpost,
    const float* __restrict__ Wlin, const float* __restrict__ blin,
    float* __restrict__ z, double* __restrict__ st, int l)
{
  __shared__ u16 wp[13312];
  __shared__ float wl[1024];
  __shared__ float etl[4096];
  __shared__ float bpo[32], bli[32];
  __shared__ float s1[16*32], s2[16*32];
  const int tid = threadIdx.x;
  const float* WpL = Wpost + (size_t)l*13312;
  for (int i=tid;i<13312;i+=1024) wp[i] = (u16)(__float_as_uint(WpL[i])>>16);
  if (tid < 1024) wl[tid] = Wlin[l*1024+tid];
  for (int i=tid;i<4096;i+=1024) etl[i] = etab[i];
  if (tid<32){ bpo[tid]=bpost[l*32+tid]; bli[tid]=blin[l*32+tid]; }
  __syncthreads();
  const int wid = tid>>6, lane = tid&63;
  const int t = lane>>3, q = lane&7;
  const int n = blockIdx.x*16 + wid;
  const int o0 = offs[n], o1 = offs[n+1];
  float bs[4]; *(float4*)bs = *(const float4*)(nbase + (size_t)n*256 + lane*4);
  float sum[4]={0,0,0,0}, sq[4]={0,0,0,0}, mn[4], mx[4];
  #pragma unroll
  for (int k=0;k<4;k++){ mn[k]=__builtin_inff(); mx[k]=-__builtin_inff(); }
  int j = o0;
  for (; j+3 < o1; j+=4){
    const int s0=esrc[j],   s1_=esrc[j+1], s2_=esrc[j+2], s3=esrc[j+3];
    const int a0=eatt[j],   a1=eatt[j+1], a2=eatt[j+2], a3=eatt[j+3];
    ushort4 p0 = *(const ushort4*)(psrcH + (size_t)s0*256 + lane*4);
    ushort4 p1 = *(const ushort4*)(psrcH + (size_t)s1_*256 + lane*4);
    ushort4 p2 = *(const ushort4*)(psrcH + (size_t)s2_*256 + lane*4);
    ushort4 p3 = *(const ushort4*)(psrcH + (size_t)s3*256 + lane*4);
    float4 e0 = *(const float4*)(etl + a0*256 + lane*4);
    float4 e1 = *(const float4*)(etl + a1*256 + lane*4);
    float4 e2 = *(const float4*)(etl + a2*256 + lane*4);
    float4 e3 = *(const float4*)(etl + a3*256 + lane*4);
    const u16* pp0=(const u16*)&p0; const float* ee0=(const float*)&e0;
    const u16* pp1=(const u16*)&p1; const float* ee1=(const float*)&e1;
    const u16* pp2=(const u16*)&p2; const float* ee2=(const float*)&e2;
    const u16* pp3=(const u16*)&p3; const float* ee3=(const float*)&e3;
    #pragma unroll
    for (int k=0;k<4;k++){
      float v0 = bs[k] + us2f(pp0[k]) + ee0[k];
      float v1 = bs[k] + us2f(pp1[k]) + ee1[k];
      float v2 = bs[k] + us2f(pp2[k]) + ee2[k];
      float v3 = bs[k] + us2f(pp3[k]) + ee3[k];
      sum[k] += (v0+v1)+(v2+v3);
      sq[k] = fmaf(v0,v0,sq[k]); sq[k] = fmaf(v1,v1,sq[k]);
      sq[k] = fmaf(v2,v2,sq[k]); sq[k] = fmaf(v3,v3,sq[k]);
      mn[k] = fminf(mn[k], fminf(fminf(v0,v1), fminf(v2,v3)));
      mx[k] = fmaxf(mx[k], fmaxf(fmaxf(v0,v1), fmaxf(v2,v3)));
    }
  }
  for (; j < o1; j++){
    const int s = esrc[j];
    const int a = eatt[j];
    ushort4 pv4 = *(const ushort4*)(psrcH + (size_t)s*256 + lane*4);
    float4 ev4 = *(const float4*)(etl + a*256 + lane*4);
    const u16* pv=(const u16*)&pv4; const float* ev=(const float*)&ev4;
    #pragma unroll
    for (int k=0;k<4;k++){
      float v = bs[k] + us2f(pv[k]) + ev[k];
      sum[k]+=v; sq[k]=fmaf(v,v,sq[k]); mn[k]=fminf(mn[k],v); mx[k]=fmaxf(mx[k],v);
    }
  }
  const int dg = o1-o0;
  const float ic = invc[n];
  float aggv[4][4];
  #pragma unroll
  for (int k=0;k<4;k++){
    float mean = sum[k]*ic;
    float ms = sq[k]*ic;
    float var = fmaxf(ms - mean*mean, 0.f);
    aggv[0][k]=mean;
    aggv[1][k]=(dg>0)?mn[k]:0.f;
    aggv[2][k]=(dg>0)?mx[k]:0.f;
    aggv[3][k]=sqrtf(var+EPSV);
  }
  const float av = amp[n], at_ = attn[n];
  float acc[4]={0,0,0,0};
  float hv[4]; *(float4*)hv = *(const float4*)(h + n*FD + q*4);
  #pragma unroll
  for (int k=0;k<4;k++){
    int c = q*4+k;
    ushort4 w4 = *(const ushort4*)&wp[(t*416+c)*4];
    const u16* ww = (const u16*)&w4;
    #pragma unroll
    for (int jj=0;jj<4;jj++)
      acc[jj] = fmaf(hv[k], us2f(ww[jj]), acc[jj]);
  }
  #pragma unroll
  for (int g=0; g<4; g++){
    #pragma unroll
    for (int k=0;k<4;k++){
      float a_ = aggv[g][k];
      int rb = 32 + g*32 + q*4 + k;
      ushort4 w0 = *(const ushort4*)&wp[(t*416+rb)*4];
      ushort4 w1 = *(const ushort4*)&wp[(t*416+rb+128)*4];
      ushort4 w2 = *(const ushort4*)&wp[(t*416+rb+256)*4];
      const u16* q0=(const u16*)&w0;
      const u16* q1=(const u16*)&w1;
      const u16* q2=(const u16*)&w2;
      #pragma unroll
      for (int jj=0;jj<4;jj++){
        float w = us2f(q0[jj]) + av*us2f(q1[jj]) + at_*us2f(q2[jj]);
        acc[jj] = fmaf(a_, w, acc[jj]);
      }
    }
  }
  #pragma unroll
  for (int jj=0;jj<4;jj++){
    acc[jj] += __shfl_xor(acc[jj], 1);
    acc[jj] += __shfl_xor(acc[jj], 2);
    acc[jj] += __shfl_xor(acc[jj], 4);
    acc[jj] += bpo[t*4+jj];
  }
  float zv = 0.f;
  #pragma unroll
  for (int dp=0; dp<32; dp++){
    float v = __shfl(acc[dp&3], (dp>>2)*8);
    zv = fmaf(v, wl[dp*32 + (lane&31)], zv);
  }
  float zfin = zv + bli[lane&31];
  if (lane < 32){
    z[n*FD + lane] = zfin;
    s1[wid*32+lane] = zfin;
    s2[wid*32+lane] = zfin*zfin;
  }
  __syncthreads();
  if (tid < 32){
    float a1=0.f, a2=0.f;
    #pragma unroll
    for (int w=0; w<16; w++){ a1 += s1[w*32+tid]; a2 += s2[w*32+tid]; }
    atomicAdd(&st[l*64+tid],    (double)a1);
    atomicAdd(&st[l*64+32+tid], (double)a2);
  }
}

// ---------------- pooling with fused final BN ----------------
__global__ __launch_bounds__(256) void k_pool2(const float* __restrict__ z, const double* __restrict__ st,
                                               const float* __restrict__ bng, const float* __restrict__ bnb,
                                               const int* __restrict__ bstart, float* __restrict__ g){
  __shared__ float acc[8][FD];
  __shared__ float scl[FD], shl[FD];
  const int b = blockIdx.x;
  const int tid = threadIdx.x;
  const int f = tid&31, rg = tid>>5;
  if (tid < FD){
    const double* stL = st + (NL-1)*64;
    double mu = stL[tid] * (1.0/(double)NN);
    double var = stL[32+tid] * (1.0/(double)NN) - mu*mu;
    float sc = bng[(NL-1)*FD+tid]*rsqrtf(fmaxf((float)var,0.f)+EPSV);
    scl[tid]=sc; shl[tid]=bnb[(NL-1)*FD+tid]-(float)mu*sc;
  }
  __syncthreads();
  const int lo = bstart[b], hi = bstart[b+1];
  float s = 0.f;
  for (int n=lo+rg; n<hi; n+=8) s += fmaxf(z[n*FD+f]*scl[f]+shl[f], 0.f);
  acc[rg][f] = s; __syncthreads();
  if (rg == 0){
    float t = 0.f;
    for (int r=0;r<8;r++) t += acc[r][f];
    g[b*FD+f] = t;
  }
}

// ---------------- head: GEMM (no input BN) ----------------
__global__ __launch_bounds__(256) void k_hgemm(const float* __restrict__ in, const float* __restrict__ W,
                                               const float* __restrict__ bias, float* __restrict__ outp,
                                               int IN){
  int o = blockIdx.x*256 + threadIdx.x;
  int b = o>>7, hh = o&127;
  float acc = bias[hh];
  for (int c=0;c<IN;c++) acc = fmaf(in[b*IN+c], W[c*NH+hh], acc);
  outp[o] = acc;
}

// ---------------- head: GEMM with fused input-BN+ReLU ----------------
__global__ __launch_bounds__(256) void k_hgemmB(const float* __restrict__ in, const float* __restrict__ W,
                                                const float* __restrict__ bias,
                                                const float* __restrict__ gvec, const float* __restrict__ bvec,
                                                float* __restrict__ outp){
  __shared__ float scf[NH], shf[NH];
  __shared__ float rows[2*NH];     // BN'd input rows for this block's 2 graphs
  const int tid = threadIdx.x;
  if (tid < NH){
    double s1=0.0, s2=0.0;
    for (int b=0;b<NB;b++){ double v=(double)in[b*NH+tid]; s1+=v; s2+=v*v; }
    double mu = s1/(double)NB;
    double var = s2/(double)NB - mu*mu;
    float sc = gvec[tid]*rsqrtf(fmaxf((float)var,0.f)+EPSV);
    scf[tid]=sc; shf[tid]=bvec[tid]-(float)mu*sc;
  }
  __syncthreads();
  const int b0 = blockIdx.x*2;     // 2 graphs per block
  for (int i=tid; i<2*NH; i+=256){
    int bb = i>>7, c = i&127;
    rows[i] = fmaxf(in[(b0+bb)*NH+c]*scf[c]+shf[c], 0.f);
  }
  __syncthreads();
  const int bb = tid>>7, hh = tid&127;
  float acc = bias[hh];
  for (int c=0;c<NH;c++) acc = fmaf(rows[bb*NH+c], W[c*NH+hh], acc);
  outp[(b0+bb)*NH+hh] = acc;
}

// ---------------- head final: fused BN + dot + sigmoid ----------------
__global__ __launch_bounds__(128) void k_hfinB(const float* __restrict__ in,
                                               const float* __restrict__ gvec, const float* __restrict__ bvec,
                                               const float* __restrict__ Wf, const float* __restrict__ bfv,
                                               float* __restrict__ out){
  __shared__ float scf[NH], shf[NH];
  const int tid = threadIdx.x;
  if (tid < NH){
    double s1=0.0, s2=0.0;
    for (int b=0;b<NB;b++){ double v=(double)in[b*NH+tid]; s1+=v; s2+=v*v; }
    double mu = s1/(double)NB;
    double var = s2/(double)NB - mu*mu;
    float sc = gvec[tid]*rsqrtf(fmaxf((float)var,0.f)+EPSV);
    scf[tid]=sc; shf[tid]=bvec[tid]-(float)mu*sc;
  }
  __syncthreads();
  if (tid < NB){
    float acc = bfv[0];
    for (int c=0;c<NH;c++)
      acc = fmaf(fmaxf(in[tid*NH+c]*scf[c]+shf[c], 0.f), Wf[c], acc);
    out[NB+tid] = acc;
    out[tid]    = 1.f/(1.f+expf(-acc));
  }
}

extern "C" void kernel_launch(void* const* d_in, const int* in_sizes, int n_in,
                              void* d_out, int out_size, void* d_ws, size_t ws_size,
                              hipStream_t stream)
{
  float* out = (float*)d_out;

  static const int EXP_SZ[24] = {16384, 524288, 262144, 16384, 1024, 256, 1536, 96,
                                 73728, 768, 39936, 96, 3072, 96, 96, 96,
                                 4096, 128, 32768, 256, 384, 384, 128, 1};
  int bad = -1;
  if (n_in != 24) bad = 24;
  else for (int i=0;i<24;i++){ if (in_sizes[i] != EXP_SZ[i]){ bad = i; break; } }
  if (bad >= 0){
    k_diag<<<1, 128, 0, stream>>>(out, 512.0f + 8.0f*(float)bad);
    return;
  }

  char* p = (char*)d_ws;
  auto carve = [&](size_t bytes)->char*{ char* r = p; p += (bytes + 255) & ~(size_t)255; return r; };
  // zero-region: flags, st, deg, cursor -> one memset
  int*    flags = (int*)carve(256);
  double* st1   = (double*)carve(3*64*8);
  int*    deg   = (int*)carve((size_t)NN*4);
  int*    cursor= (int*)carve((size_t)NN*4);
  size_t  zspan = (size_t)(((char*)cursor + ((NN*4+255)&~(size_t)255)) - (char*)flags);
  int*    offs  = (int*)carve((size_t)(NN+1)*4);
  int*    esrc  = (int*)carve((size_t)NE*4);
  int*    eatt  = (int*)carve((size_t)NE*4);
  int*    bstart= (int*)carve((size_t)(NB+1)*4);
  float*  h     = (float*)carve((size_t)NN*FD*4);
  float*  z     = (float*)carve((size_t)NN*FD*4);
  float*  nbase = (float*)carve((size_t)NN*256*4);
  u16*    psrcH = (u16*)carve((size_t)NN*256*2);
  float*  etab  = (float*)carve(4096*4);
  float*  amp   = (float*)carve((size_t)NN*4);
  float*  attn  = (float*)carve((size_t)NN*4);
  float*  invc  = (float*)carve((size_t)NN*4);
  double* lsum  = (double*)carve(8);
  float*  gp    = (float*)carve((size_t)NB*FD*4);
  float*  t0    = (float*)carve((size_t)NB*NH*4);
  float*  t1    = (float*)carve((size_t)NB*NH*4);
  float*  t2    = (float*)carve((size_t)NB*NH*4);
  int*    cx    = (int*)carve((size_t)NN*4);
  int*    cei   = (int*)carve((size_t)2*NE*4);
  int*    cea   = (int*)carve((size_t)NE*4);
  int*    cbatch= (int*)carve((size_t)NN*4);

  Jobs jb;
  float* wptr[24];
  int total = 0;
  {
    float* cur = (float*)carve(700*1024);
    for (int i=4; i<24; i++){
      jb.src[i-4] = d_in[i];
      jb.dst[i-4] = cur;
      jb.cnt[i-4] = in_sizes[i];
      wptr[i] = cur;
      cur += in_sizes[i];
      total += in_sizes[i];
    }
  }
  const size_t need = (size_t)(p - (char*)d_ws);
  if (ws_size < need){
    k_diag<<<1, 128, 0, stream>>>(out, -2000.0f - (float)(ws_size >> 20));
    return;
  }

  IJobs ij;
  ij.src[0]=d_in[0]; ij.dst[0]=cx;     ij.cnt[0]=NN;
  ij.src[1]=d_in[1]; ij.dst[1]=cei;    ij.cnt[1]=2*NE;
  ij.src[2]=d_in[2]; ij.dst[2]=cea;    ij.cnt[2]=NE;
  ij.src[3]=d_in[3]; ij.dst[3]=cbatch; ij.cnt[3]=NN;
  const int itotal = NN + 2*NE + NE + NN;

  const float* ne_f   = wptr[4];
  const float* ee_f   = wptr[5];
  const float* Wee_f  = wptr[6];
  const float* bee_f  = wptr[7];
  const float* Wpre_f = wptr[8];
  const float* bpre_f = wptr[9];
  const float* Wpost_f= wptr[10];
  const float* bpost_f= wptr[11];
  const float* Wlin_f = wptr[12];
  const float* blin_f = wptr[13];
  const float* bng_f  = wptr[14];
  const float* bnb_f  = wptr[15];
  const float* Wm0_f  = wptr[16];
  const float* bm0_f  = wptr[17];
  const float* Wmh_f  = wptr[18];
  const float* bmh_f  = wptr[19];
  const float* bnmg_f = wptr[20];
  const float* bnmb_f = wptr[21];
  const float* Wf_f   = wptr[22];
  const float* bf_f   = wptr[23];

  hipMemsetAsync(flags, 0, zspan, stream);

  k_det<<<NE/256, 256, 0, stream>>>((const u16*)d_in[4], (const int*)d_in[1], flags);
  k_cvt_int<<<(itotal+255)/256, 256, 0, stream>>>(ij, flags, deg, itotal);
  k_cvt<<<(total+255)/256, 256, 0, stream>>>(jb, flags, total);

  k_scan<<<1, 256, 0, stream>>>(deg, offs, lsum);
  k_fill<<<NE/256, 256, 0, stream>>>(cei, cei+NE, cea, offs, cursor, esrc, eatt);
  k_nodeprep<<<NN/256, 256, 0, stream>>>(deg, lsum, cbatch, amp, attn, invc, bstart);

  for (int l=0; l<NL; l++){
    k_pre<<<NN/64 + 16, 256, 0, stream>>>(z, st1, bng_f, bnb_f, cx, ne_f,
                                          ee_f, Wee_f, bee_f, Wpre_f, bpre_f,
                                          h, nbase, psrcH, etab, l);
    k_agg<<<NN/16, 1024, 0, stream>>>(nbase, psrcH, etab, esrc, eatt, offs, h, amp, attn, invc,
                                      Wpost_f, bpost_f, Wlin_f, blin_f, z, st1, l);
  }

  k_pool2<<<NB, 256, 0, stream>>>(z, st1, bng_f, bnb_f, bstart, gp);
  k_hgemm<<<32, 256, 0, stream>>>(gp, Wm0_f, bm0_f, t0, FD);
  k_hgemmB<<<32, 256, 0, stream>>>(t0, Wmh_f, bmh_f, bnmg_f, bnmb_f, t1);
  k_hgemmB<<<32, 256, 0, stream>>>(t1, Wmh_f+NH*NH, bmh_f+NH, bnmg_f+NH, bnmb_f+NH, t2);
  k_hfinB<<<1, 128, 0, stream>>>(t2, bnmg_f+2*NH, bnmb_f+2*NH, Wf_f, bf_f, out);
}